// Round 7
// baseline (8838.601 us; speedup 1.0000x reference)
//
#include <hip/hip_runtime.h>
#include <cstddef>
#include <cstdint>

// Problem dims (fixed)
#define T_   4096
#define IN_  1024
#define E_   512
#define G4_  2048   // 4*E

// ---------------------------------------------------------------------------
// fp32 tiled GEMM, 128x128 tile: C[M,N] = A[M,K] @ op(B) (+bias1+bias2)
// BT=0: B is [K,N].  BT=1: B is [N,K] (C = A @ B^T). 256 thr, 8x8/thread.
// ---------------------------------------------------------------------------
__global__ __launch_bounds__(256) void gemm_kernel(
    const float* __restrict__ A, const float* __restrict__ B, float* __restrict__ C,
    int M, int N, int K, int BT,
    const float* __restrict__ bias1, const float* __restrict__ bias2)
{
    __shared__ float As[16][128];
    __shared__ float Bs[16][132];
    const int tid = threadIdx.x;
    const int bm = blockIdx.y * 128;
    const int bn = blockIdx.x * 128;
    const int tx = tid & 15;
    const int ty = tid >> 4;
    const int lr = tid >> 1;
    const int lc = (tid & 1) * 8;
    const int bkk = tid & 15;
    const int bn0 = (tid >> 4) * 8;

    float acc[8][8];
#pragma unroll
    for (int i = 0; i < 8; ++i)
#pragma unroll
        for (int j = 0; j < 8; ++j) acc[i][j] = 0.f;

    for (int k0 = 0; k0 < K; k0 += 16) {
        float av[8], bv[8];
        {
            const float* ap = A + (size_t)(bm + lr) * K + (k0 + lc);
            *(float4*)&av[0] = *(const float4*)ap;
            *(float4*)&av[4] = *(const float4*)(ap + 4);
        }
        if (BT) {
            const float* bp = B + (size_t)(bn + lr) * K + (k0 + lc);
            *(float4*)&bv[0] = *(const float4*)bp;
            *(float4*)&bv[4] = *(const float4*)(bp + 4);
        } else {
            const float* bp = B + (size_t)(k0 + bkk) * N + (bn + bn0);
            *(float4*)&bv[0] = *(const float4*)bp;
            *(float4*)&bv[4] = *(const float4*)(bp + 4);
        }
        __syncthreads();
#pragma unroll
        for (int i = 0; i < 8; ++i) As[lc + i][lr] = av[i];
        if (BT) {
#pragma unroll
            for (int i = 0; i < 8; ++i) Bs[lc + i][lr] = bv[i];
        } else {
#pragma unroll
            for (int j = 0; j < 8; ++j) Bs[bkk][bn0 + j] = bv[j];
        }
        __syncthreads();
#pragma unroll
        for (int kk = 0; kk < 16; ++kk) {
            float a0[8], b0[8];
            *(float4*)&a0[0] = *(const float4*)&As[kk][ty * 8];
            *(float4*)&a0[4] = *(const float4*)&As[kk][ty * 8 + 4];
            *(float4*)&b0[0] = *(const float4*)&Bs[kk][tx * 8];
            *(float4*)&b0[4] = *(const float4*)&Bs[kk][tx * 8 + 4];
#pragma unroll
            for (int i = 0; i < 8; ++i)
#pragma unroll
                for (int j = 0; j < 8; ++j)
                    acc[i][j] = fmaf(a0[i], b0[j], acc[i][j]);
        }
    }

    float bias[8];
#pragma unroll
    for (int j = 0; j < 8; ++j) bias[j] = 0.f;
    if (bias1) {
#pragma unroll
        for (int j = 0; j < 8; ++j) bias[j] += bias1[bn + tx * 8 + j];
    }
    if (bias2) {
#pragma unroll
        for (int j = 0; j < 8; ++j) bias[j] += bias2[bn + tx * 8 + j];
    }
#pragma unroll
    for (int i = 0; i < 8; ++i) {
        float outv[8];
#pragma unroll
        for (int j = 0; j < 8; ++j) outv[j] = acc[i][j] + bias[j];
        float* cp = C + (size_t)(bm + ty * 8 + i) * N + (bn + tx * 8);
        *(float4*)cp = *(float4*)&outv[0];
        *(float4*)(cp + 4) = *(float4*)&outv[4];
    }
}

// ---------------------------------------------------------------------------
// fp32 tiled GEMM, 64x128 tile (2x the blocks: fills all 256 CUs when
// M=4096,N=512 -> grid 256). 256 thr, 4x8/thread.
// ---------------------------------------------------------------------------
__global__ __launch_bounds__(256) void gemm64_kernel(
    const float* __restrict__ A, const float* __restrict__ B, float* __restrict__ C,
    int M, int N, int K, int BT)
{
    __shared__ float As[16][68];
    __shared__ float Bs[16][132];
    const int tid = threadIdx.x;
    const int bm = blockIdx.y * 64;
    const int bn = blockIdx.x * 128;
    const int tx = tid & 15;
    const int ty = tid >> 4;
    const int alr = tid >> 2;
    const int alc = (tid & 3) * 4;
    const int blr = tid >> 1;
    const int blc = (tid & 1) * 8;
    const int bkk = tid & 15;
    const int bn0 = (tid >> 4) * 8;

    float acc[4][8];
#pragma unroll
    for (int i = 0; i < 4; ++i)
#pragma unroll
        for (int j = 0; j < 8; ++j) acc[i][j] = 0.f;

    for (int k0 = 0; k0 < K; k0 += 16) {
        float av[4], bv[8];
        *(float4*)&av[0] = *(const float4*)(A + (size_t)(bm + alr) * K + (k0 + alc));
        if (BT) {
            const float* bp = B + (size_t)(bn + blr) * K + (k0 + blc);
            *(float4*)&bv[0] = *(const float4*)bp;
            *(float4*)&bv[4] = *(const float4*)(bp + 4);
        } else {
            const float* bp = B + (size_t)(k0 + bkk) * N + (bn + bn0);
            *(float4*)&bv[0] = *(const float4*)bp;
            *(float4*)&bv[4] = *(const float4*)(bp + 4);
        }
        __syncthreads();
#pragma unroll
        for (int i = 0; i < 4; ++i) As[alc + i][alr] = av[i];
        if (BT) {
#pragma unroll
            for (int i = 0; i < 8; ++i) Bs[blc + i][blr] = bv[i];
        } else {
#pragma unroll
            for (int j = 0; j < 8; ++j) Bs[bkk][bn0 + j] = bv[j];
        }
        __syncthreads();
#pragma unroll
        for (int kk = 0; kk < 16; ++kk) {
            float4 a0 = *(const float4*)&As[kk][ty * 4];
            float b0[8];
            *(float4*)&b0[0] = *(const float4*)&Bs[kk][tx * 8];
            *(float4*)&b0[4] = *(const float4*)&Bs[kk][tx * 8 + 4];
            const float am[4] = {a0.x, a0.y, a0.z, a0.w};
#pragma unroll
            for (int i = 0; i < 4; ++i)
#pragma unroll
                for (int j = 0; j < 8; ++j)
                    acc[i][j] = fmaf(am[i], b0[j], acc[i][j]);
        }
    }

#pragma unroll
    for (int i = 0; i < 4; ++i) {
        float* cp = C + (size_t)(bm + ty * 4 + i) * N + (bn + tx * 8);
        *(float4*)cp = *(float4*)&acc[i][0];
        *(float4*)(cp + 4) = *(float4*)&acc[i][4];
    }
}

// ---------------------------------------------------------------------------
// Row softmax over 4096 columns, in place. One block per row.
// ---------------------------------------------------------------------------
__global__ __launch_bounds__(256) void softmax_kernel(float* __restrict__ S)
{
    __shared__ float red[8];
    float* p = S + (size_t)blockIdx.x * T_;
    const int tid = threadIdx.x;
    const int wid = tid >> 6;
    const int lane = tid & 63;
    float4 v[4];
#pragma unroll
    for (int i = 0; i < 4; ++i) v[i] = ((const float4*)p)[tid + 256 * i];
    float m = -3.0e38f;
#pragma unroll
    for (int i = 0; i < 4; ++i)
        m = fmaxf(m, fmaxf(fmaxf(v[i].x, v[i].y), fmaxf(v[i].z, v[i].w)));
#pragma unroll
    for (int o = 32; o; o >>= 1) m = fmaxf(m, __shfl_xor(m, o));
    if (lane == 0) red[wid] = m;
    __syncthreads();
    m = fmaxf(fmaxf(red[0], red[1]), fmaxf(red[2], red[3]));
    float s = 0.f;
#pragma unroll
    for (int i = 0; i < 4; ++i) {
        v[i].x = __expf(v[i].x - m); v[i].y = __expf(v[i].y - m);
        v[i].z = __expf(v[i].z - m); v[i].w = __expf(v[i].w - m);
        s += v[i].x + v[i].y + v[i].z + v[i].w;
    }
#pragma unroll
    for (int o = 32; o; o >>= 1) s += __shfl_xor(s, o);
    if (lane == 0) red[4 + wid] = s;
    __syncthreads();
    s = red[4] + red[5] + red[6] + red[7];
    const float inv = 1.f / s;
#pragma unroll
    for (int i = 0; i < 4; ++i) {
        v[i].x *= inv; v[i].y *= inv; v[i].z *= inv; v[i].w *= inv;
        ((float4*)p)[tid + 256 * i] = v[i];
    }
}

// u_mod = u * out_vec, elementwise
__global__ __launch_bounds__(256) void umod_kernel(
    const float* __restrict__ u, const float* __restrict__ ov, float* __restrict__ um)
{
    const int i = blockIdx.x * 256 + threadIdx.x;
    float4 a = ((const float4*)u)[i];
    float4 b = ((const float4*)ov)[i];
    float4 c;
    c.x = a.x * b.x; c.y = a.y * b.y; c.z = a.z * b.z; c.w = a.w * b.w;
    ((float4*)um)[i] = c;
}

// ---------------------------------------------------------------------------
// Persistent bidirectional LSTM, v7 = v6 + ADAPTIVE pacing.
// The pace (publish -> first-sample delay) is self-tuned per wave: if the
// first post-pace sample hit (no retry) decay pace by 1 tick; if any lane
// retried, grow by 2. Converges to hover at the miss threshold (~30ns
// amplitude), turning stochastic V + k*RT detection into deterministic
// pace* + 1*RT, and tracks clock/DVFS drift.
// Everything else identical to v6 (W_hh in VGPRs, 64 WGs, tagged 4B bf16
// slots, parity double-buffer, single barrier/step, early publish,
// 4-accumulator matvec).
// ---------------------------------------------------------------------------
#define NU_ 16   // hidden units per WG

__global__ __launch_bounds__(256, 1) void lstm_kernel(
    const float* __restrict__ whh_f, const float* __restrict__ whh_b,
    const float* __restrict__ xg_f, const float* __restrict__ xg_b,
    float* __restrict__ hf_out, float* __restrict__ hb_out,
    unsigned int* __restrict__ hbuf)   // [2 dirs][2 parity][512] 4B tagged
{
    __shared__ float sh[2][4 * 132];   // parity x (4 chunks x 132)

    const int tid  = threadIdx.x;
    const int dir  = blockIdx.x >> 5;   // grid=64: 0..31 fwd, 32..63 bwd
    const int w    = blockIdx.x & 31;
    const int lane = tid & 63;
    const int j    = tid >> 4;          // unit 0..15
    const int g    = (tid >> 2) & 3;    // gate 0..3 (i,f,g,o)
    const int c    = tid & 3;           // k-chunk 0..3 (128 elems)
    const int lu   = lane >> 4;         // unit-in-wave 0..3
    const int u0   = w * NU_;

    const float* whh = dir ? whh_b : whh_f;
    const float* xg  = dir ? xg_b  : xg_f;
    float* hout = dir ? hb_out : hf_out;
    unsigned int* hb = hbuf + dir * 1024;

    // One-time: this lane's 128 W_hh weights into VGPRs.
    float wreg[128];
    {
        const float* wr = whh + (size_t)(g * E_ + u0 + j) * E_ + 128 * c;
#pragma unroll
        for (int i = 0; i < 32; ++i)
            *(float4*)&wreg[4 * i] = *(const float4*)(wr + 4 * i);
    }
    for (int i = tid; i < 2 * 4 * 132; i += 256) ((float*)sh)[i] = 0.f;

    float creg = 0.f;
    const float gsc  = (g == 2) ? 2.f : 1.f;
    const float gmul = (g == 2) ? 2.f : 1.f;
    const float gadd = (g == 2) ? -1.f : 0.f;

    float xv = xg[(size_t)(dir ? (T_ - 1) : 0) * G4_ + g * E_ + u0 + j];
    unsigned int budget = 1u << 23;    // hang guard; never hit when healthy

    const int e0 = 2 * tid;                        // slots 2t, 2t+1
    const int p0 = (e0 >> 7) * 132 + (e0 & 127);   // e0 even -> p1 = p0+1

    long long tpub = (long long)__builtin_amdgcn_s_memrealtime();
    int pace = 25;   // ticks of the 100 MHz realtime clock; self-tuned below

    for (int s = 0; s < T_; ++s) {
        const int t = dir ? (T_ - 1 - s) : s;

        if (s > 0) {
            // paced sampling: first sample at ~publish + pace*
            while ((long long)__builtin_amdgcn_s_memrealtime() - tpub
                   < (long long)pace) {}
            const unsigned int tt = (unsigned int)(s - 1) & 0xFFFFu;
            const unsigned long long* src =
                (const unsigned long long*)(hb + ((s - 1) & 1) * 512);
            unsigned long long v;
            int it = 0;
            for (;;) {
                ++it;
                v = __hip_atomic_load(src + tid, __ATOMIC_RELAXED,
                                      __HIP_MEMORY_SCOPE_AGENT);
                const unsigned int lo = (unsigned int)v;
                const unsigned int hi = (unsigned int)(v >> 32);
                if (((lo >> 16) == tt && (hi >> 16) == tt) || !--budget) break;
            }
            // adapt: any retry in this wave -> +2; clean hit -> -1
            const unsigned long long miss = __ballot(it > 1);
            pace += miss ? 2 : -1;
            pace = pace < 5 ? 5 : (pace > 120 ? 120 : pace);

            float2 hv;
            hv.x = __uint_as_float((unsigned int)v << 16);          // bf16->f32
            hv.y = __uint_as_float((unsigned int)(v >> 32) << 16);
            *(float2*)&sh[s & 1][p0] = hv;
        }
        __syncthreads();   // the only per-step barrier

        // matvec: 128 reg-weight FMAs, 4 independent accumulators
        const float* hc = &sh[s & 1][132 * c];
        float sx = 0.f, sy = 0.f, sz = 0.f, sw = 0.f;
#pragma unroll
        for (int i = 0; i < 32; ++i) {
            const float4 h4 = *(const float4*)&hc[4 * i];
            sx = fmaf(wreg[4 * i + 0], h4.x, sx);
            sy = fmaf(wreg[4 * i + 1], h4.y, sy);
            sz = fmaf(wreg[4 * i + 2], h4.z, sz);
            sw = fmaf(wreg[4 * i + 3], h4.w, sw);
        }
        float sum = (sx + sy) + (sz + sw);
        // reduce across the 4 chunk-lanes
        sum += __shfl_xor(sum, 1);
        sum += __shfl_xor(sum, 2);

        // branchless gate: sig for i,f,o; tanh (=2*sig(2x)-1) for g
        const float xx = (sum + xv) * gsc;
        const float rr = __builtin_amdgcn_rcpf(1.f + __expf(-xx));
        const float val = fmaf(rr, gmul, gadd);

        // gather the 4 gates of this lane's unit (within-wave shuffles)
        const int base = 16 * lu + c;
        const float iv = __shfl(val, base);
        const float fv = __shfl(val, base + 4);
        const float gv = __shfl(val, base + 8);
        const float ov = __shfl(val, base + 12);
        creg = fmaf(fv, creg, iv * gv);      // redundant across the 16 unit-lanes
        const float th = fmaf(2.f, __builtin_amdgcn_rcpf(1.f + __expf(-2.f * creg)), -1.f);
        const float h = ov * th;

        // early publish: one lane per unit, pre-barrier
        if ((tid & 15) == 0) {
            const unsigned int ub = __float_as_uint(h);
            const unsigned int b16 = (ub + 0x7FFFu + ((ub >> 16) & 1u)) >> 16; // RNE
            const unsigned int pkt = (((unsigned int)s & 0xFFFFu) << 16) | b16;
            __hip_atomic_store(hb + (s & 1) * 512 + u0 + j, pkt,
                               __ATOMIC_RELAXED, __HIP_MEMORY_SCOPE_AGENT);
            hout[(size_t)t * E_ + u0 + j] = h;   // fp32 h for the projection
        }
        tpub = (long long)__builtin_amdgcn_s_memrealtime();

        if (s + 1 < T_)
            xv = xg[(size_t)(dir ? (T_ - 2 - s) : (s + 1)) * G4_ + g * E_ + u0 + j];
    }
}

// score[t] = dot(hf[t], fw[0:512]) + dot(hb[t], fw[512:1024]) + fb
__global__ __launch_bounds__(256) void final_kernel(
    const float* __restrict__ hf, const float* __restrict__ hb,
    const float* __restrict__ fw, const float* __restrict__ fb,
    float* __restrict__ out)
{
    const int t = blockIdx.x * 4 + (threadIdx.x >> 6);
    const int lane = threadIdx.x & 63;
    float s = 0.f;
#pragma unroll
    for (int i = 0; i < 8; ++i) {
        const int e = lane + 64 * i;
        s += hf[(size_t)t * E_ + e] * fw[e];
    }
#pragma unroll
    for (int i = 0; i < 8; ++i) {
        const int e = lane + 64 * i;
        s += hb[(size_t)t * E_ + e] * fw[E_ + e];
    }
#pragma unroll
    for (int o = 32; o; o >>= 1) s += __shfl_xor(s, o);
    if (lane == 0) out[t] = s + fb[0];
}

// ---------------------------------------------------------------------------
// Workspace layout (floats; 1 MB = 262144 floats). Peak ~96 MB via overlays:
//   a [0,8MB) b [8,16) u [16,24) S [24,88) ov [88,96)
//   um [24,32)  xf [32,64)  xb [64,96)  hf [0,8)  hb [8,16)
//   tagged hbuf @96MB (2048 x 4B = 8KB)
// ---------------------------------------------------------------------------
extern "C" void kernel_launch(void* const* d_in, const int* in_sizes, int n_in,
                              void* d_out, int out_size, void* d_ws, size_t ws_size,
                              hipStream_t stream)
{
    const float* x     = (const float*)d_in[0];
    const float* Amat  = (const float*)d_in[1];
    const float* Bmat  = (const float*)d_in[2];
    const float* Umat  = (const float*)d_in[3];
    const float* wih_f = (const float*)d_in[4];
    const float* whh_f = (const float*)d_in[5];
    const float* bih_f = (const float*)d_in[6];
    const float* bhh_f = (const float*)d_in[7];
    const float* wih_b = (const float*)d_in[8];
    const float* whh_b = (const float*)d_in[9];
    const float* bih_b = (const float*)d_in[10];
    const float* bhh_b = (const float*)d_in[11];
    const float* fw    = (const float*)d_in[12];
    const float* fb    = (const float*)d_in[13];
    float* out = (float*)d_out;
    float* ws = (float*)d_ws;

    const size_t MBf = 262144;
    float* a_  = ws;
    float* b_  = ws + 8 * MBf;
    float* u_  = ws + 16 * MBf;
    float* S_  = ws + 24 * MBf;
    float* ov_ = ws + 88 * MBf;
    float* um_ = ws + 24 * MBf;
    float* xf_ = ws + 32 * MBf;
    float* xb_ = ws + 64 * MBf;
    float* hf_ = ws;
    float* hb_ = ws + 8 * MBf;
    unsigned int* hbuf_ = (unsigned int*)(ws + 96 * MBf);

    dim3 blk(256);

    gemm64_kernel<<<dim3(4, 64), blk, 0, stream>>>(x, Amat, a_, T_, E_, IN_, 0);
    gemm64_kernel<<<dim3(4, 64), blk, 0, stream>>>(x, Bmat, b_, T_, E_, IN_, 0);
    gemm64_kernel<<<dim3(4, 64), blk, 0, stream>>>(x, Umat, u_, T_, E_, IN_, 0);
    gemm_kernel<<<dim3(32, 32), blk, 0, stream>>>(u_, a_, S_, T_, T_, E_, 1, nullptr, nullptr);
    softmax_kernel<<<dim3(T_), blk, 0, stream>>>(S_);
    gemm64_kernel<<<dim3(4, 64), blk, 0, stream>>>(S_, b_, ov_, T_, E_, T_, 0);
    umod_kernel<<<dim3(2048), blk, 0, stream>>>(u_, ov_, um_);
    gemm_kernel<<<dim3(16, 32), blk, 0, stream>>>(um_, wih_f, xf_, T_, G4_, E_, 1, bih_f, bhh_f);
    gemm_kernel<<<dim3(16, 32), blk, 0, stream>>>(um_, wih_b, xb_, T_, G4_, E_, 1, bih_b, bhh_b);
    lstm_kernel<<<dim3(64), blk, 0, stream>>>(whh_f, whh_b, xf_, xb_, hf_, hb_, hbuf_);
    final_kernel<<<dim3(1024), blk, 0, stream>>>(hf_, hb_, fw, fb, out);
}

// Round 8
// 7556.221 us; speedup vs baseline: 1.1697x; 1.1697x over previous
//
#include <hip/hip_runtime.h>
#include <cstddef>
#include <cstdint>

// Problem dims (fixed)
#define T_   4096
#define IN_  1024
#define E_   512
#define G4_  2048   // 4*E

typedef unsigned short ushort_t;
typedef __attribute__((ext_vector_type(8))) short bf16x8;   // 8 bf16 = 4 VGPRs
typedef __attribute__((ext_vector_type(4))) float f32x4;    // MFMA acc

__device__ __forceinline__ ushort_t rne_bf16(float x) {
    unsigned int u = __float_as_uint(x);
    return (ushort_t)((u + 0x7FFFu + ((u >> 16) & 1u)) >> 16);
}
__device__ __forceinline__ float bf2f(ushort_t h) {
    return __uint_as_float((unsigned int)h << 16);
}

// ---------------------------------------------------------------------------
// Split-bf16 MFMA GEMM.  C[M,N] = sum_k A[m,k]*B[n,k]  (+bias1[n]+bias2[n])
// A given as (Ah[,Al]) row-major [M][K] bf16; B as (Bh,Bl) row-major [N][K].
// nA=2: 3 products (Ah.Bh + Ah.Bl + Al.Bh) ~ fp32 precision.
// nA=1: 2 products (Ah.Bh + Ah.Bl).
// Outputs: Cf fp32 and/or Ch/Cl bf16 (h/l split), any nullable.
// Tile 128x128, BK=32, 4 waves (2x2 of 64x64), 16x16x32 bf16 MFMA.
// Frag layouts per guide (m89/m91-verified): A/B[idx=lane&15][k=quad*8+j],
// C/D col=lane&15, row=quad*4+reg.
// LDS row stride 40 ushorts (80B): 16B-group = (5*row+q)%8 -> 2-way max (free).
// ---------------------------------------------------------------------------
__global__ __launch_bounds__(256) void mfma_gemm(
    const ushort_t* __restrict__ Ah, const ushort_t* __restrict__ Al,
    const ushort_t* __restrict__ Bh, const ushort_t* __restrict__ Bl,
    float* __restrict__ Cf, ushort_t* __restrict__ Ch, ushort_t* __restrict__ Cl,
    int M, int N, int K, int nA,
    const float* __restrict__ bias1, const float* __restrict__ bias2)
{
    __shared__ ushort_t sAh[128 * 40], sAl[128 * 40];
    __shared__ ushort_t sBh[128 * 40], sBl[128 * 40];   // 40KB total

    const int tid  = threadIdx.x;
    const int wv   = tid >> 6;
    const int lane = tid & 63;
    const int quad = lane >> 4;
    const int l16  = lane & 15;
    const int bm = blockIdx.y * 128, bn = blockIdx.x * 128;
    const int wrow = (wv & 1) * 64, wcol = (wv >> 1) * 64;

    f32x4 acc[4][4];
#pragma unroll
    for (int i = 0; i < 4; ++i)
#pragma unroll
        for (int j = 0; j < 4; ++j) acc[i][j] = (f32x4){0.f, 0.f, 0.f, 0.f};

    const int r0 = tid >> 2;            // staging row 0..63 (and +64)
    const int ks = (tid & 3) * 8;       // k-offset in ushorts

    for (int k0 = 0; k0 < K; k0 += 32) {
        const size_t ga0 = (size_t)(bm + r0) * K + k0 + ks;
        const size_t ga1 = (size_t)(bm + r0 + 64) * K + k0 + ks;
        const size_t gb0 = (size_t)(bn + r0) * K + k0 + ks;
        const size_t gb1 = (size_t)(bn + r0 + 64) * K + k0 + ks;
        uint4 vA0 = *(const uint4*)(Ah + ga0);
        uint4 vA1 = *(const uint4*)(Ah + ga1);
        uint4 vB0h = *(const uint4*)(Bh + gb0);
        uint4 vB1h = *(const uint4*)(Bh + gb1);
        uint4 vB0l = *(const uint4*)(Bl + gb0);
        uint4 vB1l = *(const uint4*)(Bl + gb1);
        uint4 vA0l, vA1l;
        if (nA == 2) { vA0l = *(const uint4*)(Al + ga0); vA1l = *(const uint4*)(Al + ga1); }
        __syncthreads();   // protect previous iteration's frag reads
        *(uint4*)&sAh[r0 * 40 + ks] = vA0;
        *(uint4*)&sAh[(r0 + 64) * 40 + ks] = vA1;
        *(uint4*)&sBh[r0 * 40 + ks] = vB0h;
        *(uint4*)&sBh[(r0 + 64) * 40 + ks] = vB1h;
        *(uint4*)&sBl[r0 * 40 + ks] = vB0l;
        *(uint4*)&sBl[(r0 + 64) * 40 + ks] = vB1l;
        if (nA == 2) {
            *(uint4*)&sAl[r0 * 40 + ks] = vA0l;
            *(uint4*)&sAl[(r0 + 64) * 40 + ks] = vA1l;
        }
        __syncthreads();

        bf16x8 afh[4], afl[4], bfh[4], bfl[4];
#pragma unroll
        for (int f = 0; f < 4; ++f) {
            const int ar = (wrow + f * 16 + l16) * 40 + quad * 8;
            const int br = (wcol + f * 16 + l16) * 40 + quad * 8;
            afh[f] = *(const bf16x8*)&sAh[ar];
            bfh[f] = *(const bf16x8*)&sBh[br];
            bfl[f] = *(const bf16x8*)&sBl[br];
            if (nA == 2) afl[f] = *(const bf16x8*)&sAl[ar];
        }
#pragma unroll
        for (int fi = 0; fi < 4; ++fi)
#pragma unroll
            for (int fj = 0; fj < 4; ++fj) {
                acc[fi][fj] = __builtin_amdgcn_mfma_f32_16x16x32_bf16(
                    afh[fi], bfh[fj], acc[fi][fj], 0, 0, 0);
                acc[fi][fj] = __builtin_amdgcn_mfma_f32_16x16x32_bf16(
                    afh[fi], bfl[fj], acc[fi][fj], 0, 0, 0);
                if (nA == 2)
                    acc[fi][fj] = __builtin_amdgcn_mfma_f32_16x16x32_bf16(
                        afl[fi], bfh[fj], acc[fi][fj], 0, 0, 0);
            }
    }

#pragma unroll
    for (int fi = 0; fi < 4; ++fi)
#pragma unroll
        for (int fj = 0; fj < 4; ++fj) {
            const int col = bn + wcol + fj * 16 + l16;
            float bv = 0.f;
            if (bias1) bv += bias1[col];
            if (bias2) bv += bias2[col];
#pragma unroll
            for (int r = 0; r < 4; ++r) {
                const int row = bm + wrow + fi * 16 + quad * 4 + r;
                const float v = acc[fi][fj][r] + bv;
                const size_t o = (size_t)row * N + col;
                if (Cf) Cf[o] = v;
                if (Ch) {
                    const ushort_t h = rne_bf16(v);
                    Ch[o] = h;
                    if (Cl) Cl[o] = rne_bf16(v - bf2f(h));
                }
            }
        }
}

// fp32 -> (hi, lo) bf16 split, elementwise (4 elems/thread)
__global__ __launch_bounds__(256) void conv_hl(
    const float* __restrict__ in, ushort_t* __restrict__ oh, ushort_t* __restrict__ ol)
{
    const size_t i = ((size_t)blockIdx.x * 256 + threadIdx.x) * 4;
    float4 v = *(const float4*)(in + i);
    ushort4 h, l;
    h.x = rne_bf16(v.x); l.x = rne_bf16(v.x - bf2f(h.x));
    h.y = rne_bf16(v.y); l.y = rne_bf16(v.y - bf2f(h.y));
    h.z = rne_bf16(v.z); l.z = rne_bf16(v.z - bf2f(h.z));
    h.w = rne_bf16(v.w); l.w = rne_bf16(v.w - bf2f(h.w));
    *(ushort4*)(oh + i) = h;
    *(ushort4*)(ol + i) = l;
}

// fp32 [R][C] -> transposed (hi, lo) bf16 [C][R]
__global__ __launch_bounds__(256) void conv_hl_T(
    const float* __restrict__ in, ushort_t* __restrict__ oh, ushort_t* __restrict__ ol,
    int R, int C)
{
    __shared__ float t[32][33];
    const int tx = threadIdx.x & 31, ty = threadIdx.x >> 5;  // 32x8
    const int gr = blockIdx.y * 32, gc = blockIdx.x * 32;
#pragma unroll
    for (int i = 0; i < 4; ++i)
        t[ty + 8 * i][tx] = in[(size_t)(gr + ty + 8 * i) * C + gc + tx];
    __syncthreads();
#pragma unroll
    for (int i = 0; i < 4; ++i) {
        const int oc = gc + ty + 8 * i;
        const float v = t[tx][ty + 8 * i];
        const ushort_t h = rne_bf16(v);
        oh[(size_t)oc * R + gr + tx] = h;
        ol[(size_t)oc * R + gr + tx] = rne_bf16(v - bf2f(h));
    }
}

// Row softmax over 4096 cols; fp32 in, bf16 out (separate buffer).
__global__ __launch_bounds__(256) void softmax_kernel(
    const float* __restrict__ S, ushort_t* __restrict__ P)
{
    __shared__ float red[8];
    const float* p = S + (size_t)blockIdx.x * T_;
    ushort_t* pr = P + (size_t)blockIdx.x * T_;
    const int tid = threadIdx.x;
    const int wid = tid >> 6;
    const int lane = tid & 63;
    float4 v[4];
#pragma unroll
    for (int i = 0; i < 4; ++i) v[i] = ((const float4*)p)[tid + 256 * i];
    float m = -3.0e38f;
#pragma unroll
    for (int i = 0; i < 4; ++i)
        m = fmaxf(m, fmaxf(fmaxf(v[i].x, v[i].y), fmaxf(v[i].z, v[i].w)));
#pragma unroll
    for (int o = 32; o; o >>= 1) m = fmaxf(m, __shfl_xor(m, o));
    if (lane == 0) red[wid] = m;
    __syncthreads();
    m = fmaxf(fmaxf(red[0], red[1]), fmaxf(red[2], red[3]));
    float s = 0.f;
#pragma unroll
    for (int i = 0; i < 4; ++i) {
        v[i].x = __expf(v[i].x - m); v[i].y = __expf(v[i].y - m);
        v[i].z = __expf(v[i].z - m); v[i].w = __expf(v[i].w - m);
        s += v[i].x + v[i].y + v[i].z + v[i].w;
    }
#pragma unroll
    for (int o = 32; o; o >>= 1) s += __shfl_xor(s, o);
    if (lane == 0) red[4 + wid] = s;
    __syncthreads();
    s = red[4] + red[5] + red[6] + red[7];
    const float inv = 1.f / s;
#pragma unroll
    for (int i = 0; i < 4; ++i) {
        ushort4 o4;
        o4.x = rne_bf16(v[i].x * inv); o4.y = rne_bf16(v[i].y * inv);
        o4.z = rne_bf16(v[i].z * inv); o4.w = rne_bf16(v[i].w * inv);
        ((ushort4*)pr)[tid + 256 * i] = o4;
    }
}

// um = (uh+ul) * ov, output as h/l split (4 elems/thread)
__global__ __launch_bounds__(256) void umod_kernel(
    const ushort_t* __restrict__ uh, const ushort_t* __restrict__ ul,
    const float* __restrict__ ov,
    ushort_t* __restrict__ mh, ushort_t* __restrict__ ml)
{
    const size_t i = ((size_t)blockIdx.x * 256 + threadIdx.x) * 4;
    ushort4 h4 = *(const ushort4*)(uh + i);
    ushort4 l4 = *(const ushort4*)(ul + i);
    float4 o = *(const float4*)(ov + i);
    float4 m;
    m.x = (bf2f(h4.x) + bf2f(l4.x)) * o.x;
    m.y = (bf2f(h4.y) + bf2f(l4.y)) * o.y;
    m.z = (bf2f(h4.z) + bf2f(l4.z)) * o.z;
    m.w = (bf2f(h4.w) + bf2f(l4.w)) * o.w;
    ushort4 oh, ol;
    oh.x = rne_bf16(m.x); ol.x = rne_bf16(m.x - bf2f(oh.x));
    oh.y = rne_bf16(m.y); ol.y = rne_bf16(m.y - bf2f(oh.y));
    oh.z = rne_bf16(m.z); ol.z = rne_bf16(m.z - bf2f(oh.z));
    oh.w = rne_bf16(m.w); ol.w = rne_bf16(m.w - bf2f(oh.w));
    *(ushort4*)(mh + i) = oh;
    *(ushort4*)(ml + i) = ol;
}

// ---------------------------------------------------------------------------
// Persistent bidirectional LSTM, v6 (BEST: fixed pace 25). Xg now bf16.
// ---------------------------------------------------------------------------
#define NU_ 16
#define PACE_TICKS 25L  // ~250ns @100MHz; v7's adaptive pace regressed (miss-penalty asymmetry)

__global__ __launch_bounds__(256, 1) void lstm_kernel(
    const float* __restrict__ whh_f, const float* __restrict__ whh_b,
    const ushort_t* __restrict__ xg_f, const ushort_t* __restrict__ xg_b,
    float* __restrict__ hf_out, float* __restrict__ hb_out,
    unsigned int* __restrict__ hbuf)   // [2 dirs][2 parity][512] 4B tagged
{
    __shared__ float sh[2][4 * 132];

    const int tid  = threadIdx.x;
    const int dir  = blockIdx.x >> 5;
    const int w    = blockIdx.x & 31;
    const int lane = tid & 63;
    const int j    = tid >> 4;
    const int g    = (tid >> 2) & 3;
    const int c    = tid & 3;
    const int lu   = lane >> 4;
    const int u0   = w * NU_;

    const float* whh = dir ? whh_b : whh_f;
    const ushort_t* xg = dir ? xg_b : xg_f;
    float* hout = dir ? hb_out : hf_out;
    unsigned int* hb = hbuf + dir * 1024;

    float wreg[128];
    {
        const float* wr = whh + (size_t)(g * E_ + u0 + j) * E_ + 128 * c;
#pragma unroll
        for (int i = 0; i < 32; ++i)
            *(float4*)&wreg[4 * i] = *(const float4*)(wr + 4 * i);
    }
    for (int i = tid; i < 2 * 4 * 132; i += 256) ((float*)sh)[i] = 0.f;

    float creg = 0.f;
    const float gsc  = (g == 2) ? 2.f : 1.f;
    const float gmul = (g == 2) ? 2.f : 1.f;
    const float gadd = (g == 2) ? -1.f : 0.f;

    float xv = bf2f(xg[(size_t)(dir ? (T_ - 1) : 0) * G4_ + g * E_ + u0 + j]);
    unsigned int budget = 1u << 23;

    const int e0 = 2 * tid;
    const int p0 = (e0 >> 7) * 132 + (e0 & 127);

    long long tpub = (long long)__builtin_amdgcn_s_memrealtime();

    for (int s = 0; s < T_; ++s) {
        const int t = dir ? (T_ - 1 - s) : s;

        if (s > 0) {
            while ((long long)__builtin_amdgcn_s_memrealtime() - tpub < PACE_TICKS) {}
            const unsigned int tt = (unsigned int)(s - 1) & 0xFFFFu;
            const unsigned long long* src =
                (const unsigned long long*)(hb + ((s - 1) & 1) * 512);
            unsigned long long v;
            for (;;) {
                v = __hip_atomic_load(src + tid, __ATOMIC_RELAXED,
                                      __HIP_MEMORY_SCOPE_AGENT);
                const unsigned int lo = (unsigned int)v;
                const unsigned int hi = (unsigned int)(v >> 32);
                if (((lo >> 16) == tt && (hi >> 16) == tt) || !--budget) break;
            }
            float2 hv;
            hv.x = __uint_as_float((unsigned int)v << 16);
            hv.y = __uint_as_float((unsigned int)(v >> 32) << 16);
            *(float2*)&sh[s & 1][p0] = hv;
        }
        __syncthreads();

        const float* hc = &sh[s & 1][132 * c];
        float sx = 0.f, sy = 0.f, sz = 0.f, sw = 0.f;
#pragma unroll
        for (int i = 0; i < 32; ++i) {
            const float4 h4 = *(const float4*)&hc[4 * i];
            sx = fmaf(wreg[4 * i + 0], h4.x, sx);
            sy = fmaf(wreg[4 * i + 1], h4.y, sy);
            sz = fmaf(wreg[4 * i + 2], h4.z, sz);
            sw = fmaf(wreg[4 * i + 3], h4.w, sw);
        }
        float sum = (sx + sy) + (sz + sw);
        sum += __shfl_xor(sum, 1);
        sum += __shfl_xor(sum, 2);

        const float xx = (sum + xv) * gsc;
        const float rr = __builtin_amdgcn_rcpf(1.f + __expf(-xx));
        const float val = fmaf(rr, gmul, gadd);

        const int base = 16 * lu + c;
        const float iv = __shfl(val, base);
        const float fv = __shfl(val, base + 4);
        const float gv = __shfl(val, base + 8);
        const float ov = __shfl(val, base + 12);
        creg = fmaf(fv, creg, iv * gv);
        const float th = fmaf(2.f, __builtin_amdgcn_rcpf(1.f + __expf(-2.f * creg)), -1.f);
        const float h = ov * th;

        if ((tid & 15) == 0) {
            const unsigned int ub = __float_as_uint(h);
            const unsigned int b16 = (ub + 0x7FFFu + ((ub >> 16) & 1u)) >> 16;
            const unsigned int pkt = (((unsigned int)s & 0xFFFFu) << 16) | b16;
            __hip_atomic_store(hb + (s & 1) * 512 + u0 + j, pkt,
                               __ATOMIC_RELAXED, __HIP_MEMORY_SCOPE_AGENT);
            hout[(size_t)t * E_ + u0 + j] = h;
        }
        tpub = (long long)__builtin_amdgcn_s_memrealtime();

        if (s + 1 < T_)
            xv = bf2f(xg[(size_t)(dir ? (T_ - 2 - s) : (s + 1)) * G4_ + g * E_ + u0 + j]);
    }
}

// score[t] = dot(hf[t], fw[0:512]) + dot(hb[t], fw[512:1024]) + fb
__global__ __launch_bounds__(256) void final_kernel(
    const float* __restrict__ hf, const float* __restrict__ hb,
    const float* __restrict__ fw, const float* __restrict__ fb,
    float* __restrict__ out)
{
    const int t = blockIdx.x * 4 + (threadIdx.x >> 6);
    const int lane = threadIdx.x & 63;
    float s = 0.f;
#pragma unroll
    for (int i = 0; i < 8; ++i) {
        const int e = lane + 64 * i;
        s += hf[(size_t)t * E_ + e] * fw[e];
    }
#pragma unroll
    for (int i = 0; i < 8; ++i) {
        const int e = lane + 64 * i;
        s += hb[(size_t)t * E_ + e] * fw[E_ + e];
    }
#pragma unroll
    for (int o = 32; o; o >>= 1) s += __shfl_xor(s, o);
    if (lane == 0) out[t] = s + fb[0];
}

// ---------------------------------------------------------------------------
// Workspace layout (MiB offsets; peak 120 MiB + 8KB):
//  uh@0-4 ul@4-8 | b@8-16 | xh@16-24 xl@24-32 | ATh@32 ATl@33 BTh@34 BTl@35
//  UTh@36 UTl@37 | ah@38-42 al@42-46 | bTh@46-50 bTl@50-54 | S@56-120
//  Ph@8-40 (over dead b/xh/xl/matT/ah-head, after they die)
//  ov@56-64, umh@64-68, uml@68-72, wfh@72 wfl@74 wbh@76 wbl@78 (over dead S)
//  xfg@80-96 xbg@96-112 (bf16) | hf@0-8 hb@8-16 (over dead uh/ul/Ph) | hbuf@112
// ---------------------------------------------------------------------------
extern "C" void kernel_launch(void* const* d_in, const int* in_sizes, int n_in,
                              void* d_out, int out_size, void* d_ws, size_t ws_size,
                              hipStream_t stream)
{
    const float* x     = (const float*)d_in[0];
    const float* Amat  = (const float*)d_in[1];
    const float* Bmat  = (const float*)d_in[2];
    const float* Umat  = (const float*)d_in[3];
    const float* wih_f = (const float*)d_in[4];
    const float* whh_f = (const float*)d_in[5];
    const float* bih_f = (const float*)d_in[6];
    const float* bhh_f = (const float*)d_in[7];
    const float* wih_b = (const float*)d_in[8];
    const float* whh_b = (const float*)d_in[9];
    const float* bih_b = (const float*)d_in[10];
    const float* bhh_b = (const float*)d_in[11];
    const float* fw    = (const float*)d_in[12];
    const float* fb    = (const float*)d_in[13];
    float* out = (float*)d_out;
    char* wsb = (char*)d_ws;
    const size_t MB = 1048576ull;

    ushort_t* uh  = (ushort_t*)(wsb + 0 * MB);
    ushort_t* ul  = (ushort_t*)(wsb + 4 * MB);
    float*    bfp = (float*)   (wsb + 8 * MB);
    ushort_t* xh  = (ushort_t*)(wsb + 16 * MB);
    ushort_t* xl  = (ushort_t*)(wsb + 24 * MB);
    ushort_t* ATh = (ushort_t*)(wsb + 32 * MB);
    ushort_t* ATl = (ushort_t*)(wsb + 33 * MB);
    ushort_t* BTh = (ushort_t*)(wsb + 34 * MB);
    ushort_t* BTl = (ushort_t*)(wsb + 35 * MB);
    ushort_t* UTh = (ushort_t*)(wsb + 36 * MB);
    ushort_t* UTl = (ushort_t*)(wsb + 37 * MB);
    ushort_t* ah  = (ushort_t*)(wsb + 38 * MB);
    ushort_t* al  = (ushort_t*)(wsb + 42 * MB);
    ushort_t* bTh = (ushort_t*)(wsb + 46 * MB);
    ushort_t* bTl = (ushort_t*)(wsb + 50 * MB);
    float*    S_  = (float*)   (wsb + 56 * MB);
    ushort_t* Ph  = (ushort_t*)(wsb + 8 * MB);    // overlays dead b/xh/xl/matT
    float*    ov_ = (float*)   (wsb + 56 * MB);   // overlays dead S head
    ushort_t* umh = (ushort_t*)(wsb + 64 * MB);
    ushort_t* uml = (ushort_t*)(wsb + 68 * MB);
    ushort_t* wfh = (ushort_t*)(wsb + 72 * MB);
    ushort_t* wfl = (ushort_t*)(wsb + 74 * MB);
    ushort_t* wbh = (ushort_t*)(wsb + 76 * MB);
    ushort_t* wbl = (ushort_t*)(wsb + 78 * MB);
    ushort_t* xfg = (ushort_t*)(wsb + 80 * MB);
    ushort_t* xbg = (ushort_t*)(wsb + 96 * MB);
    float*    hf_ = (float*)   (wsb + 0 * MB);    // overlays dead uh/ul
    float*    hb_ = (float*)   (wsb + 8 * MB);    // overlays dead Ph head
    unsigned int* hbuf_ = (unsigned int*)(wsb + 112 * MB);

    dim3 blk(256);

    // splits
    conv_hl<<<dim3(4096), blk, 0, stream>>>(x, xh, xl);                       // 4096x1024
    conv_hl_T<<<dim3(16, 32), blk, 0, stream>>>(Amat, ATh, ATl, 1024, 512);
    conv_hl_T<<<dim3(16, 32), blk, 0, stream>>>(Bmat, BTh, BTl, 1024, 512);
    conv_hl_T<<<dim3(16, 32), blk, 0, stream>>>(Umat, UTh, UTl, 1024, 512);
    // a,b,u = x @ {A,B,U}
    mfma_gemm<<<dim3(4, 32), blk, 0, stream>>>(xh, xl, ATh, ATl, nullptr, ah, al,
                                               T_, E_, IN_, 2, nullptr, nullptr);
    mfma_gemm<<<dim3(4, 32), blk, 0, stream>>>(xh, xl, BTh, BTl, bfp, nullptr, nullptr,
                                               T_, E_, IN_, 2, nullptr, nullptr);
    mfma_gemm<<<dim3(4, 32), blk, 0, stream>>>(xh, xl, UTh, UTl, nullptr, uh, ul,
                                               T_, E_, IN_, 2, nullptr, nullptr);
    // S = u a^T
    mfma_gemm<<<dim3(32, 32), blk, 0, stream>>>(uh, ul, ah, al, S_, nullptr, nullptr,
                                                T_, T_, E_, 2, nullptr, nullptr);
    // b^T split (before softmax so Ph can overlay b)
    conv_hl_T<<<dim3(16, 128), blk, 0, stream>>>(bfp, bTh, bTl, 4096, 512);
    softmax_kernel<<<dim3(T_), blk, 0, stream>>>(S_, Ph);
    // out_vec = P b
    mfma_gemm<<<dim3(4, 32), blk, 0, stream>>>(Ph, nullptr, bTh, bTl, ov_, nullptr, nullptr,
                                               T_, E_, T_, 1, nullptr, nullptr);
    umod_kernel<<<dim3(2048), blk, 0, stream>>>(uh, ul, ov_, umh, uml);
    conv_hl<<<dim3(1024), blk, 0, stream>>>(wih_f, wfh, wfl);                 // 2048x512
    conv_hl<<<dim3(1024), blk, 0, stream>>>(wih_b, wbh, wbl);
    // Xg = um w_ih^T + biases (bf16 out)
    mfma_gemm<<<dim3(16, 32), blk, 0, stream>>>(umh, uml, wfh, wfl, nullptr, xfg, nullptr,
                                                T_, G4_, E_, 2, bih_f, bhh_f);
    mfma_gemm<<<dim3(16, 32), blk, 0, stream>>>(umh, uml, wbh, wbl, nullptr, xbg, nullptr,
                                                T_, G4_, E_, 2, bih_b, bhh_b);
    lstm_kernel<<<dim3(64), blk, 0, stream>>>(whh_f, whh_b, xfg, xbg, hf_, hb_, hbuf_);
    final_kernel<<<dim3(1024), blk, 0, stream>>>(hf_, hb_, fw, fb, out);
}

// Round 9
// 6738.829 us; speedup vs baseline: 1.3116x; 1.1213x over previous
//
#include <hip/hip_runtime.h>
#include <cstddef>
#include <cstdint>

// Problem dims (fixed)
#define T_   4096
#define IN_  1024
#define E_   512
#define G4_  2048   // 4*E

typedef unsigned short ushort_t;
typedef __attribute__((ext_vector_type(8))) short bf16x8;   // 8 bf16 = 4 VGPRs
typedef __attribute__((ext_vector_type(4))) float f32x4;    // MFMA acc

__device__ __forceinline__ ushort_t rne_bf16(float x) {
    unsigned int u = __float_as_uint(x);
    return (ushort_t)((u + 0x7FFFu + ((u >> 16) & 1u)) >> 16);
}
__device__ __forceinline__ float bf2f(ushort_t h) {
    return __uint_as_float((unsigned int)h << 16);
}

// 8B load that bypasses L1 but may HIT the local XCD's L2 (sc0 only).
// Agent-scope atomic loads emit sc0+sc1 (bypass L2 -> MALL RT ~600-900cy);
// this stays at L2-hit latency (~200cy) when producer is on the same XCD.
__device__ __forceinline__ unsigned long long load_l2_u64(const unsigned long long* p) {
    unsigned long long v;
    asm volatile("global_load_dwordx2 %0, %1, off sc0\n\ts_waitcnt vmcnt(0)"
                 : "=v"(v) : "v"(p) : "memory");
    return v;
}

// ---------------------------------------------------------------------------
// Split-bf16 MFMA GEMM.  C[M,N] = sum_k A[m,k]*B[n,k]  (+bias1[n]+bias2[n])
// (unchanged from round 8; see comments there)
// ---------------------------------------------------------------------------
__global__ __launch_bounds__(256) void mfma_gemm(
    const ushort_t* __restrict__ Ah, const ushort_t* __restrict__ Al,
    const ushort_t* __restrict__ Bh, const ushort_t* __restrict__ Bl,
    float* __restrict__ Cf, ushort_t* __restrict__ Ch, ushort_t* __restrict__ Cl,
    int M, int N, int K, int nA,
    const float* __restrict__ bias1, const float* __restrict__ bias2)
{
    __shared__ ushort_t sAh[128 * 40], sAl[128 * 40];
    __shared__ ushort_t sBh[128 * 40], sBl[128 * 40];

    const int tid  = threadIdx.x;
    const int wv   = tid >> 6;
    const int lane = tid & 63;
    const int quad = lane >> 4;
    const int l16  = lane & 15;
    const int bm = blockIdx.y * 128, bn = blockIdx.x * 128;
    const int wrow = (wv & 1) * 64, wcol = (wv >> 1) * 64;

    f32x4 acc[4][4];
#pragma unroll
    for (int i = 0; i < 4; ++i)
#pragma unroll
        for (int j = 0; j < 4; ++j) acc[i][j] = (f32x4){0.f, 0.f, 0.f, 0.f};

    const int r0 = tid >> 2;
    const int ks = (tid & 3) * 8;

    for (int k0 = 0; k0 < K; k0 += 32) {
        const size_t ga0 = (size_t)(bm + r0) * K + k0 + ks;
        const size_t ga1 = (size_t)(bm + r0 + 64) * K + k0 + ks;
        const size_t gb0 = (size_t)(bn + r0) * K + k0 + ks;
        const size_t gb1 = (size_t)(bn + r0 + 64) * K + k0 + ks;
        uint4 vA0 = *(const uint4*)(Ah + ga0);
        uint4 vA1 = *(const uint4*)(Ah + ga1);
        uint4 vB0h = *(const uint4*)(Bh + gb0);
        uint4 vB1h = *(const uint4*)(Bh + gb1);
        uint4 vB0l = *(const uint4*)(Bl + gb0);
        uint4 vB1l = *(const uint4*)(Bl + gb1);
        uint4 vA0l, vA1l;
        if (nA == 2) { vA0l = *(const uint4*)(Al + ga0); vA1l = *(const uint4*)(Al + ga1); }
        __syncthreads();
        *(uint4*)&sAh[r0 * 40 + ks] = vA0;
        *(uint4*)&sAh[(r0 + 64) * 40 + ks] = vA1;
        *(uint4*)&sBh[r0 * 40 + ks] = vB0h;
        *(uint4*)&sBh[(r0 + 64) * 40 + ks] = vB1h;
        *(uint4*)&sBl[r0 * 40 + ks] = vB0l;
        *(uint4*)&sBl[(r0 + 64) * 40 + ks] = vB1l;
        if (nA == 2) {
            *(uint4*)&sAl[r0 * 40 + ks] = vA0l;
            *(uint4*)&sAl[(r0 + 64) * 40 + ks] = vA1l;
        }
        __syncthreads();

        bf16x8 afh[4], afl[4], bfh[4], bfl[4];
#pragma unroll
        for (int f = 0; f < 4; ++f) {
            const int ar = (wrow + f * 16 + l16) * 40 + quad * 8;
            const int br = (wcol + f * 16 + l16) * 40 + quad * 8;
            afh[f] = *(const bf16x8*)&sAh[ar];
            bfh[f] = *(const bf16x8*)&sBh[br];
            bfl[f] = *(const bf16x8*)&sBl[br];
            if (nA == 2) afl[f] = *(const bf16x8*)&sAl[ar];
        }
#pragma unroll
        for (int fi = 0; fi < 4; ++fi)
#pragma unroll
            for (int fj = 0; fj < 4; ++fj) {
                acc[fi][fj] = __builtin_amdgcn_mfma_f32_16x16x32_bf16(
                    afh[fi], bfh[fj], acc[fi][fj], 0, 0, 0);
                acc[fi][fj] = __builtin_amdgcn_mfma_f32_16x16x32_bf16(
                    afh[fi], bfl[fj], acc[fi][fj], 0, 0, 0);
                if (nA == 2)
                    acc[fi][fj] = __builtin_amdgcn_mfma_f32_16x16x32_bf16(
                        afl[fi], bfh[fj], acc[fi][fj], 0, 0, 0);
            }
    }

#pragma unroll
    for (int fi = 0; fi < 4; ++fi)
#pragma unroll
        for (int fj = 0; fj < 4; ++fj) {
            const int col = bn + wcol + fj * 16 + l16;
            float bv = 0.f;
            if (bias1) bv += bias1[col];
            if (bias2) bv += bias2[col];
#pragma unroll
            for (int r = 0; r < 4; ++r) {
                const int row = bm + wrow + fi * 16 + quad * 4 + r;
                const float v = acc[fi][fj][r] + bv;
                const size_t o = (size_t)row * N + col;
                if (Cf) Cf[o] = v;
                if (Ch) {
                    const ushort_t h = rne_bf16(v);
                    Ch[o] = h;
                    if (Cl) Cl[o] = rne_bf16(v - bf2f(h));
                }
            }
        }
}

// fp32 -> (hi, lo) bf16 split, elementwise (4 elems/thread)
__global__ __launch_bounds__(256) void conv_hl(
    const float* __restrict__ in, ushort_t* __restrict__ oh, ushort_t* __restrict__ ol)
{
    const size_t i = ((size_t)blockIdx.x * 256 + threadIdx.x) * 4;
    float4 v = *(const float4*)(in + i);
    ushort4 h, l;
    h.x = rne_bf16(v.x); l.x = rne_bf16(v.x - bf2f(h.x));
    h.y = rne_bf16(v.y); l.y = rne_bf16(v.y - bf2f(h.y));
    h.z = rne_bf16(v.z); l.z = rne_bf16(v.z - bf2f(h.z));
    h.w = rne_bf16(v.w); l.w = rne_bf16(v.w - bf2f(h.w));
    *(ushort4*)(oh + i) = h;
    *(ushort4*)(ol + i) = l;
}

// fp32 [R][C] -> transposed (hi, lo) bf16 [C][R]
__global__ __launch_bounds__(256) void conv_hl_T(
    const float* __restrict__ in, ushort_t* __restrict__ oh, ushort_t* __restrict__ ol,
    int R, int C)
{
    __shared__ float t[32][33];
    const int tx = threadIdx.x & 31, ty = threadIdx.x >> 5;  // 32x8
    const int gr = blockIdx.y * 32, gc = blockIdx.x * 32;
#pragma unroll
    for (int i = 0; i < 4; ++i)
        t[ty + 8 * i][tx] = in[(size_t)(gr + ty + 8 * i) * C + gc + tx];
    __syncthreads();
#pragma unroll
    for (int i = 0; i < 4; ++i) {
        const int oc = gc + ty + 8 * i;
        const float v = t[tx][ty + 8 * i];
        const ushort_t h = rne_bf16(v);
        oh[(size_t)oc * R + gr + tx] = h;
        ol[(size_t)oc * R + gr + tx] = rne_bf16(v - bf2f(h));
    }
}

// Row softmax over 4096 cols; fp32 in, bf16 out.
__global__ __launch_bounds__(256) void softmax_kernel(
    const float* __restrict__ S, ushort_t* __restrict__ P)
{
    __shared__ float red[8];
    const float* p = S + (size_t)blockIdx.x * T_;
    ushort_t* pr = P + (size_t)blockIdx.x * T_;
    const int tid = threadIdx.x;
    const int wid = tid >> 6;
    const int lane = tid & 63;
    float4 v[4];
#pragma unroll
    for (int i = 0; i < 4; ++i) v[i] = ((const float4*)p)[tid + 256 * i];
    float m = -3.0e38f;
#pragma unroll
    for (int i = 0; i < 4; ++i)
        m = fmaxf(m, fmaxf(fmaxf(v[i].x, v[i].y), fmaxf(v[i].z, v[i].w)));
#pragma unroll
    for (int o = 32; o; o >>= 1) m = fmaxf(m, __shfl_xor(m, o));
    if (lane == 0) red[wid] = m;
    __syncthreads();
    m = fmaxf(fmaxf(red[0], red[1]), fmaxf(red[2], red[3]));
    float s = 0.f;
#pragma unroll
    for (int i = 0; i < 4; ++i) {
        v[i].x = __expf(v[i].x - m); v[i].y = __expf(v[i].y - m);
        v[i].z = __expf(v[i].z - m); v[i].w = __expf(v[i].w - m);
        s += v[i].x + v[i].y + v[i].z + v[i].w;
    }
#pragma unroll
    for (int o = 32; o; o >>= 1) s += __shfl_xor(s, o);
    if (lane == 0) red[4 + wid] = s;
    __syncthreads();
    s = red[4] + red[5] + red[6] + red[7];
    const float inv = 1.f / s;
#pragma unroll
    for (int i = 0; i < 4; ++i) {
        ushort4 o4;
        o4.x = rne_bf16(v[i].x * inv); o4.y = rne_bf16(v[i].y * inv);
        o4.z = rne_bf16(v[i].z * inv); o4.w = rne_bf16(v[i].w * inv);
        ((ushort4*)pr)[tid + 256 * i] = o4;
    }
}

// um = (uh+ul) * ov, output as h/l split
__global__ __launch_bounds__(256) void umod_kernel(
    const ushort_t* __restrict__ uh, const ushort_t* __restrict__ ul,
    const float* __restrict__ ov,
    ushort_t* __restrict__ mh, ushort_t* __restrict__ ml)
{
    const size_t i = ((size_t)blockIdx.x * 256 + threadIdx.x) * 4;
    ushort4 h4 = *(const ushort4*)(uh + i);
    ushort4 l4 = *(const ushort4*)(ul + i);
    float4 o = *(const float4*)(ov + i);
    float4 m;
    m.x = (bf2f(h4.x) + bf2f(l4.x)) * o.x;
    m.y = (bf2f(h4.y) + bf2f(l4.y)) * o.y;
    m.z = (bf2f(h4.z) + bf2f(l4.z)) * o.z;
    m.w = (bf2f(h4.w) + bf2f(l4.w)) * o.w;
    ushort4 oh, ol;
    oh.x = rne_bf16(m.x); ol.x = rne_bf16(m.x - bf2f(oh.x));
    oh.y = rne_bf16(m.y); ol.y = rne_bf16(m.y - bf2f(oh.y));
    oh.z = rne_bf16(m.z); ol.z = rne_bf16(m.z - bf2f(oh.z));
    oh.w = rne_bf16(m.w); ol.w = rne_bf16(m.w - bf2f(oh.w));
    *(ushort4*)(mh + i) = oh;
    *(ushort4*)(ml + i) = ol;
}

// ---------------------------------------------------------------------------
// Persistent bidirectional LSTM, v9: XCD-local h-exchange.
// Grid 256; only blocks with blockIdx%8 in {0,1} work (dir = blockIdx%8,
// w = blockIdx>>3). Under the observed round-robin block->XCD mapping this
// puts each direction's 32 WGs on ONE XCD, so h-exchange stays in that
// XCD's L2:
//   publish: dual store -- plain (write-through -> local L2) + agent (MALL,
//            authoritative);
//   poll:    sc0-only 8B loads (L1-bypass, L2-hit ~200cy) with fallback to
//            agent loads after 6 misses; 8 consecutive fallback steps
//            permanently demote the wave to the v8 agent path.
// Mapping is a perf heuristic only -- correctness holds either way (G16).
// Pace: 8 ticks local (miss penalty now cheap), 25 agent (v7 lesson:
// miss-penalty asymmetry punishes aggressive pacing on the MALL path).
// ---------------------------------------------------------------------------
#define NU_ 16
#define PACE_L 8L
#define PACE_A 25L

__global__ __launch_bounds__(256, 1) void lstm_kernel(
    const float* __restrict__ whh_f, const float* __restrict__ whh_b,
    const ushort_t* __restrict__ xg_f, const ushort_t* __restrict__ xg_b,
    float* __restrict__ hf_out, float* __restrict__ hb_out,
    unsigned int* __restrict__ hbuf,   // agent/MALL: [2 dirs][2 parity][512]
    unsigned int* __restrict__ lbuf)   // XCD-local:  [2 dirs][2 parity][512]
{
    const int xcd = blockIdx.x & 7;
    if (xcd >= 2) return;               // 192 helper blocks exit immediately
    const int dir = xcd;                // fwd on XCD0, bwd on XCD1 (if mapping holds)
    const int w   = blockIdx.x >> 3;    // 0..31

    __shared__ float sh[2][4 * 132];

    const int tid  = threadIdx.x;
    const int lane = tid & 63;
    const int j    = tid >> 4;
    const int g    = (tid >> 2) & 3;
    const int c    = tid & 3;
    const int lu   = lane >> 4;
    const int u0   = w * NU_;

    const float* whh = dir ? whh_b : whh_f;
    const ushort_t* xg = dir ? xg_b : xg_f;
    float* hout = dir ? hb_out : hf_out;
    unsigned int* hb = hbuf + dir * 1024;
    unsigned int* lb = lbuf + dir * 1024;

    float wreg[128];
    {
        const float* wr = whh + (size_t)(g * E_ + u0 + j) * E_ + 128 * c;
#pragma unroll
        for (int i = 0; i < 32; ++i)
            *(float4*)&wreg[4 * i] = *(const float4*)(wr + 4 * i);
    }
    for (int i = tid; i < 2 * 4 * 132; i += 256) ((float*)sh)[i] = 0.f;

    float creg = 0.f;
    const float gsc  = (g == 2) ? 2.f : 1.f;
    const float gmul = (g == 2) ? 2.f : 1.f;
    const float gadd = (g == 2) ? -1.f : 0.f;

    float xv = bf2f(xg[(size_t)(dir ? (T_ - 1) : 0) * G4_ + g * E_ + u0 + j]);
    unsigned int budget = 1u << 23;

    const int e0 = 2 * tid;
    const int p0 = (e0 >> 7) * 132 + (e0 & 127);

    long long tpub = (long long)__builtin_amdgcn_s_memrealtime();
    int use_local = 1, failcnt = 0;

    for (int s = 0; s < T_; ++s) {
        const int t = dir ? (T_ - 1 - s) : s;

        if (s > 0) {
            const long long pt = use_local ? PACE_L : PACE_A;
            while ((long long)__builtin_amdgcn_s_memrealtime() - tpub < pt) {}
            const unsigned int tt = (unsigned int)(s - 1) & 0xFFFFu;
            const unsigned long long* srcL =
                (const unsigned long long*)(lb + ((s - 1) & 1) * 512);
            const unsigned long long* srcA =
                (const unsigned long long*)(hb + ((s - 1) & 1) * 512);
            unsigned long long v;
            if (use_local) {
                bool fell = false;
                int spins = 0;
                for (;;) {
                    v = load_l2_u64(srcL + tid);
                    if (((unsigned int)v >> 16) == tt &&
                        ((unsigned int)(v >> 32) >> 16) == tt) break;
                    if (++spins >= 6) {
                        v = __hip_atomic_load(srcA + tid, __ATOMIC_RELAXED,
                                              __HIP_MEMORY_SCOPE_AGENT);
                        if (((unsigned int)v >> 16) == tt &&
                            ((unsigned int)(v >> 32) >> 16) == tt) { fell = true; break; }
                        if (!--budget) break;
                    }
                }
                if (__ballot(fell)) { if (++failcnt >= 8) use_local = 0; }
                else failcnt = 0;
            } else {
                for (;;) {
                    v = __hip_atomic_load(srcA + tid, __ATOMIC_RELAXED,
                                          __HIP_MEMORY_SCOPE_AGENT);
                    if ((((unsigned int)v >> 16) == tt &&
                         ((unsigned int)(v >> 32) >> 16) == tt) || !--budget) break;
                }
            }
            float2 hv;
            hv.x = __uint_as_float((unsigned int)v << 16);
            hv.y = __uint_as_float((unsigned int)(v >> 32) << 16);
            *(float2*)&sh[s & 1][p0] = hv;
        }
        __syncthreads();

        const float* hc = &sh[s & 1][132 * c];
        float sx = 0.f, sy = 0.f, sz = 0.f, sw = 0.f;
#pragma unroll
        for (int i = 0; i < 32; ++i) {
            const float4 h4 = *(const float4*)&hc[4 * i];
            sx = fmaf(wreg[4 * i + 0], h4.x, sx);
            sy = fmaf(wreg[4 * i + 1], h4.y, sy);
            sz = fmaf(wreg[4 * i + 2], h4.z, sz);
            sw = fmaf(wreg[4 * i + 3], h4.w, sw);
        }
        float sum = (sx + sy) + (sz + sw);
        sum += __shfl_xor(sum, 1);
        sum += __shfl_xor(sum, 2);

        const float xx = (sum + xv) * gsc;
        const float rr = __builtin_amdgcn_rcpf(1.f + __expf(-xx));
        const float val = fmaf(rr, gmul, gadd);

        const int base = 16 * lu + c;
        const float iv = __shfl(val, base);
        const float fv = __shfl(val, base + 4);
        const float gv = __shfl(val, base + 8);
        const float ov = __shfl(val, base + 12);
        creg = fmaf(fv, creg, iv * gv);
        const float th = fmaf(2.f, __builtin_amdgcn_rcpf(1.f + __expf(-2.f * creg)), -1.f);
        const float h = ov * th;

        if ((tid & 15) == 0) {
            const unsigned int ub = __float_as_uint(h);
            const unsigned int b16 = (ub + 0x7FFFu + ((ub >> 16) & 1u)) >> 16;
            const unsigned int pkt = (((unsigned int)s & 0xFFFFu) << 16) | b16;
            // local first (write-through -> this XCD's L2), then authoritative
            __hip_atomic_store(lb + (s & 1) * 512 + u0 + j, pkt,
                               __ATOMIC_RELAXED, __HIP_MEMORY_SCOPE_WORKGROUP);
            __hip_atomic_store(hb + (s & 1) * 512 + u0 + j, pkt,
                               __ATOMIC_RELAXED, __HIP_MEMORY_SCOPE_AGENT);
            hout[(size_t)t * E_ + u0 + j] = h;
        }
        tpub = (long long)__builtin_amdgcn_s_memrealtime();

        if (s + 1 < T_)
            xv = bf2f(xg[(size_t)(dir ? (T_ - 2 - s) : (s + 1)) * G4_ + g * E_ + u0 + j]);
    }
}

// score[t] = dot(hf[t], fw[0:512]) + dot(hb[t], fw[512:1024]) + fb
__global__ __launch_bounds__(256) void final_kernel(
    const float* __restrict__ hf, const float* __restrict__ hb,
    const float* __restrict__ fw, const float* __restrict__ fb,
    float* __restrict__ out)
{
    const int t = blockIdx.x * 4 + (threadIdx.x >> 6);
    const int lane = threadIdx.x & 63;
    float s = 0.f;
#pragma unroll
    for (int i = 0; i < 8; ++i) {
        const int e = lane + 64 * i;
        s += hf[(size_t)t * E_ + e] * fw[e];
    }
#pragma unroll
    for (int i = 0; i < 8; ++i) {
        const int e = lane + 64 * i;
        s += hb[(size_t)t * E_ + e] * fw[E_ + e];
    }
#pragma unroll
    for (int o = 32; o; o >>= 1) s += __shfl_xor(s, o);
    if (lane == 0) out[t] = s + fb[0];
}

// ---------------------------------------------------------------------------
// Workspace layout (MiB offsets; peak 120 MiB):
//  uh@0-4 ul@4-8 | b@8-16 | xh@16-24 xl@24-32 | ATh@32 ATl@33 BTh@34 BTl@35
//  UTh@36 UTl@37 | ah@38-42 al@42-46 | bTh@46-50 bTl@50-54 | S@56-120
//  Ph@8-40 | ov@56-64 umh@64-68 uml@68-72 wfh@72 wfl@74 wbh@76 wbl@78
//  xfg@80-96 xbg@96-112 | hf@0-8 hb@8-16 | hbuf@112 (8KB) lbuf@113 (8KB)
// ---------------------------------------------------------------------------
extern "C" void kernel_launch(void* const* d_in, const int* in_sizes, int n_in,
                              void* d_out, int out_size, void* d_ws, size_t ws_size,
                              hipStream_t stream)
{
    const float* x     = (const float*)d_in[0];
    const float* Amat  = (const float*)d_in[1];
    const float* Bmat  = (const float*)d_in[2];
    const float* Umat  = (const float*)d_in[3];
    const float* wih_f = (const float*)d_in[4];
    const float* whh_f = (const float*)d_in[5];
    const float* bih_f = (const float*)d_in[6];
    const float* bhh_f = (const float*)d_in[7];
    const float* wih_b = (const float*)d_in[8];
    const float* whh_b = (const float*)d_in[9];
    const float* bih_b = (const float*)d_in[10];
    const float* bhh_b = (const float*)d_in[11];
    const float* fw    = (const float*)d_in[12];
    const float* fb    = (const float*)d_in[13];
    float* out = (float*)d_out;
    char* wsb = (char*)d_ws;
    const size_t MB = 1048576ull;

    ushort_t* uh  = (ushort_t*)(wsb + 0 * MB);
    ushort_t* ul  = (ushort_t*)(wsb + 4 * MB);
    float*    bfp = (float*)   (wsb + 8 * MB);
    ushort_t* xh  = (ushort_t*)(wsb + 16 * MB);
    ushort_t* xl  = (ushort_t*)(wsb + 24 * MB);
    ushort_t* ATh = (ushort_t*)(wsb + 32 * MB);
    ushort_t* ATl = (ushort_t*)(wsb + 33 * MB);
    ushort_t* BTh = (ushort_t*)(wsb + 34 * MB);
    ushort_t* BTl = (ushort_t*)(wsb + 35 * MB);
    ushort_t* UTh = (ushort_t*)(wsb + 36 * MB);
    ushort_t* UTl = (ushort_t*)(wsb + 37 * MB);
    ushort_t* ah  = (ushort_t*)(wsb + 38 * MB);
    ushort_t* al  = (ushort_t*)(wsb + 42 * MB);
    ushort_t* bTh = (ushort_t*)(wsb + 46 * MB);
    ushort_t* bTl = (ushort_t*)(wsb + 50 * MB);
    float*    S_  = (float*)   (wsb + 56 * MB);
    ushort_t* Ph  = (ushort_t*)(wsb + 8 * MB);
    float*    ov_ = (float*)   (wsb + 56 * MB);
    ushort_t* umh = (ushort_t*)(wsb + 64 * MB);
    ushort_t* uml = (ushort_t*)(wsb + 68 * MB);
    ushort_t* wfh = (ushort_t*)(wsb + 72 * MB);
    ushort_t* wfl = (ushort_t*)(wsb + 74 * MB);
    ushort_t* wbh = (ushort_t*)(wsb + 76 * MB);
    ushort_t* wbl = (ushort_t*)(wsb + 78 * MB);
    ushort_t* xfg = (ushort_t*)(wsb + 80 * MB);
    ushort_t* xbg = (ushort_t*)(wsb + 96 * MB);
    float*    hf_ = (float*)   (wsb + 0 * MB);
    float*    hb_ = (float*)   (wsb + 8 * MB);
    unsigned int* hbuf_ = (unsigned int*)(wsb + 112 * MB);
    unsigned int* lbuf_ = (unsigned int*)(wsb + 113 * MB);

    dim3 blk(256);

    conv_hl<<<dim3(4096), blk, 0, stream>>>(x, xh, xl);
    conv_hl_T<<<dim3(16, 32), blk, 0, stream>>>(Amat, ATh, ATl, 1024, 512);
    conv_hl_T<<<dim3(16, 32), blk, 0, stream>>>(Bmat, BTh, BTl, 1024, 512);
    conv_hl_T<<<dim3(16, 32), blk, 0, stream>>>(Umat, UTh, UTl, 1024, 512);
    mfma_gemm<<<dim3(4, 32), blk, 0, stream>>>(xh, xl, ATh, ATl, nullptr, ah, al,
                                               T_, E_, IN_, 2, nullptr, nullptr);
    mfma_gemm<<<dim3(4, 32), blk, 0, stream>>>(xh, xl, BTh, BTl, bfp, nullptr, nullptr,
                                               T_, E_, IN_, 2, nullptr, nullptr);
    mfma_gemm<<<dim3(4, 32), blk, 0, stream>>>(xh, xl, UTh, UTl, nullptr, uh, ul,
                                               T_, E_, IN_, 2, nullptr, nullptr);
    mfma_gemm<<<dim3(32, 32), blk, 0, stream>>>(uh, ul, ah, al, S_, nullptr, nullptr,
                                                T_, T_, E_, 2, nullptr, nullptr);
    conv_hl_T<<<dim3(16, 128), blk, 0, stream>>>(bfp, bTh, bTl, 4096, 512);
    softmax_kernel<<<dim3(T_), blk, 0, stream>>>(S_, Ph);
    mfma_gemm<<<dim3(4, 32), blk, 0, stream>>>(Ph, nullptr, bTh, bTl, ov_, nullptr, nullptr,
                                               T_, E_, T_, 1, nullptr, nullptr);
    umod_kernel<<<dim3(2048), blk, 0, stream>>>(uh, ul, ov_, umh, uml);
    conv_hl<<<dim3(1024), blk, 0, stream>>>(wih_f, wfh, wfl);
    conv_hl<<<dim3(1024), blk, 0, stream>>>(wih_b, wbh, wbl);
    mfma_gemm<<<dim3(16, 32), blk, 0, stream>>>(umh, uml, wfh, wfl, nullptr, xfg, nullptr,
                                                T_, G4_, E_, 2, bih_f, bhh_f);
    mfma_gemm<<<dim3(16, 32), blk, 0, stream>>>(umh, uml, wbh, wbl, nullptr, xbg, nullptr,
                                                T_, G4_, E_, 2, bih_b, bhh_b);
    lstm_kernel<<<dim3(256), blk, 0, stream>>>(whh_f, whh_b, xfg, xbg, hf_, hb_,
                                               hbuf_, lbuf_);
    final_kernel<<<dim3(1024), blk, 0, stream>>>(hf_, hb_, fw, fb, out);
}